// Round 6
// baseline (45.767 us; speedup 1.0000x reference)
//
#include <hip/hip_runtime.h>

#define B_ 4
#define R_ 48
#define VR_ 96
#define NBLK (B_ * R_ * 12)     // 2304 blocks: (b, r, quad); 4 waves = 4 s-cells

typedef float v2f __attribute__((ext_vector_type(2)));

// ---------------------------------------------------------------------------
// Detect cmaps element width from its first 256 bytes (wave-parallel, lanes
// 0..63). int32 layout: bytes at i%4!=0 all zero; f32 layout: contains
// 0x80/0x3F exponent bytes; bool layout: random 0/1 bytes, some nonzero,
// none > 1. Deterministic for fixed inputs; every block computes the same.
__device__ __forceinline__ int detect_stride4(const unsigned char* cm, int t) {
  const unsigned int d = ((const unsigned int*)cm)[t];
  const unsigned int b1 = (d >> 8) & 0xff, b2 = (d >> 16) & 0xff, b3 = d >> 24;
  const unsigned long long nzm = __ballot((b1 | b2 | b3) != 0);
  const unsigned long long bigm = __ballot((b1 > 1) || (b2 > 1) || (b3 > 1));
  return (bigm != 0ull || nzm == 0ull) ? 1 : 0;
}

// ---------------------------------------------------------------------------
// Single fused kernel: gather + per-cell min-distance + masked-mean
// accumulation. One wave per (b,r,s) cell, 4 cells/block sharing the g1 row.
// Each block folds its 4 cells into ONE float atomicAdd on out[b]
// (pre-divided by the batch mask count, so out accumulates to the final
// masked mean). No fences; 4 target addresses; adds overlap execution.
// out must be zeroed before launch (memset node in the graph).
__global__ __launch_bounds__(256) void fused_all_kernel(
    const float* __restrict__ v1s, const float* __restrict__ v2s,
    const int* __restrict__ rid_to_vid, const unsigned char* __restrict__ cm,
    float* __restrict__ out, int N) {
  const int bid = blockIdx.x;              // b*(48*12) + r*12 + quad
  const int b = bid / (R_ * 12);
  const int rem = bid % (R_ * 12);
  const int r = rem / 12;
  const int quad = rem % 12;
  const int t = threadIdx.x;
  const int w = t >> 6, lane = t & 63;
  const int s = quad * 4 + w;
  const int cellIdx = (b * R_ + r) * R_ + s;

  __shared__ int stride4_s;
  if (t < 64) {
    const int s4 = detect_stride4(cm, t);
    if (t == 0) stride4_s = s4;
  }
  __syncthreads();
  const int stride4 = stride4_s;
  const unsigned int* cm32 = (const unsigned int*)cm;

  const bool active = stride4 ? (cm32[cellIdx] != 0u) : (cm[cellIdx] != 0);

  // block-wide any-active; ~6% of blocks are all-masked and contribute 0
  __shared__ int flags[4];
  if (lane == 0) flags[w] = active ? 1 : 0;
  __syncthreads();
  if ((flags[0] | flags[1] | flags[2] | flags[3]) == 0) return;  // uniform

  // per-batch mask count (each thread 9 cells; L2-hit, shared across blocks)
  int cnt = 0;
  const int base = b * R_ * R_;
  for (int i = t; i < R_ * R_; i += 256)
    cnt += stride4 ? (cm32[base + i] != 0u ? 1 : 0) : (cm[base + i] != 0 ? 1 : 0);
#pragma unroll
  for (int off = 32; off > 0; off >>= 1) cnt += __shfl_down(cnt, off, 64);
  __shared__ int wcnt[4];
  if (lane == 0) wcnt[w] = cnt;

  // cooperative gather into SoA LDS: s1 = g1 row r; s2[k] = g2 row quad*4+k
  __shared__ float s1[3 * VR_];
  __shared__ float s2[4][3 * VR_];
  if (t < VR_) {
    const int idx = rid_to_vid[r * VR_ + t];
    const float* src = v1s + ((size_t)b * N + idx) * 3;
    s1[t] = src[0]; s1[VR_ + t] = src[1]; s1[2 * VR_ + t] = src[2];
  }
  for (int p = t; p < 4 * VR_; p += 256) {
    const int srow = p / VR_, v = p % VR_;
    const int idx = rid_to_vid[(quad * 4 + srow) * VR_ + v];
    const float* src = v2s + ((size_t)b * N + idx) * 3;
    s2[srow][v] = src[0]; s2[srow][VR_ + v] = src[1]; s2[srow][2 * VR_ + v] = src[2];
  }
  __syncthreads();   // covers wcnt + gather

  float mind = 0.0f;
  if (active) {                             // wave-uniform; inactive waves idle
    const float* r2 = s2[w];
    const int hi = lane >> 3, lo = lane & 7;  // 8x8 lane grid, 12x12 pair tile

    float Ax[12], Ay[12], Az[12];
    v2f Bx[6], By[6], Bz[6];
#pragma unroll
    for (int k = 0; k < 3; ++k) {
      *(float4*)&Ax[4 * k] = *(const float4*)(s1           + hi * 12 + 4 * k);
      *(float4*)&Ay[4 * k] = *(const float4*)(s1 +     VR_ + hi * 12 + 4 * k);
      *(float4*)&Az[4 * k] = *(const float4*)(s1 + 2 * VR_ + hi * 12 + 4 * k);
      *(float4*)&Bx[2 * k] = *(const float4*)(r2           + lo * 12 + 4 * k);
      *(float4*)&By[2 * k] = *(const float4*)(r2 +     VR_ + lo * 12 + 4 * k);
      *(float4*)&Bz[2 * k] = *(const float4*)(r2 + 2 * VR_ + lo * 12 + 4 * k);
    }

    float acc[4] = {3.4e38f, 3.4e38f, 3.4e38f, 3.4e38f};
#pragma unroll
    for (int i = 0; i < 12; ++i) {
      const v2f axx = {Ax[i], Ax[i]};
      const v2f ayy = {Ay[i], Ay[i]};
      const v2f azz = {Az[i], Az[i]};
#pragma unroll
      for (int j = 0; j < 6; ++j) {
        const v2f dx = axx - Bx[j];
        const v2f dy = ayy - By[j];
        const v2f dz = azz - Bz[j];
        const v2f d2 = dx * dx + dy * dy + dz * dz;
        acc[j & 3] = fminf(acc[j & 3], fminf(d2.x, d2.y));   // v_min3
      }
    }
    float mind2 = fminf(fminf(acc[0], acc[1]), fminf(acc[2], acc[3]));
#pragma unroll
    for (int off = 32; off > 0; off >>= 1)
      mind2 = fminf(mind2, __shfl_down(mind2, off, 64));
    mind = sqrtf(fmaxf(mind2, 0.0f));
  }

  // block partial: Σ of 4 cell mins, pre-divided by batch count, one atomic
  __shared__ float sm[4];
  if (lane == 0) sm[w] = mind;              // inactive waves wrote mind=0
  __syncthreads();
  if (t == 0) {
    const float count_b = (float)(wcnt[0] + wcnt[1] + wcnt[2] + wcnt[3]);
    const float partial = (sm[0] + sm[1] + sm[2] + sm[3]) / count_b;
    atomicAdd(&out[b], partial);            // no fence; 4 addrs total
  }
}

// ---------------------------------------------------------------------------
extern "C" void kernel_launch(void* const* d_in, const int* in_sizes, int n_in,
                              void* d_out, int out_size, void* d_ws, size_t ws_size,
                              hipStream_t stream) {
  const float* v1s = (const float*)d_in[0];
  const float* v2s = (const float*)d_in[1];
  const unsigned char* cmaps = (const unsigned char*)d_in[2];
  const int* rid_to_vid = (const int*)d_in[3];
  float* out = (float*)d_out;

  const int N = in_sizes[0] / (B_ * 3);

  hipMemsetAsync(out, 0, (size_t)out_size * sizeof(float), stream);
  fused_all_kernel<<<NBLK, 256, 0, stream>>>(
      v1s, v2s, rid_to_vid, cmaps, out, N);
}

// Round 7
// 26.540 us; speedup vs baseline: 1.7245x; 1.7245x over previous
//
#include <hip/hip_runtime.h>

#define B_ 4
#define R_ 48
#define VR_ 96
#define NBLK (B_ * 12 * 12)      // 576 blocks: (b, rq, sq) 4x4 cell tiles

typedef float v2f __attribute__((ext_vector_type(2)));
struct F3 { float x, y, z; };    // 12B, 4B-aligned -> global_load_dwordx3

// ---------------------------------------------------------------------------
// Detect cmaps element width from its first 256 bytes (wave-parallel, lanes
// 0..63). int32 layout: bytes at i%4!=0 all zero; f32 layout: contains
// 0x80/0x3F exponent bytes; bool layout: random 0/1 bytes, some nonzero,
// none > 1. Deterministic for fixed inputs; every block computes the same.
__device__ __forceinline__ int detect_stride4(const unsigned char* cm, int t) {
  const unsigned int d = ((const unsigned int*)cm)[t];
  const unsigned int b1 = (d >> 8) & 0xff, b2 = (d >> 16) & 0xff, b3 = d >> 24;
  const unsigned long long nzm = __ballot((b1 | b2 | b3) != 0);
  const unsigned long long bigm = __ballot((b1 > 1) || (b2 > 1) || (b3 > 1));
  return (bigm != 0ull || nzm == 0ull) ? 1 : 0;
}

// ---------------------------------------------------------------------------
// Kernel 1: fused gather + min-distance over a 4x4 cell tile. 4 waves/block;
// wave w owns g1 row (rq*4+w) and iterates the 4 s-cells. Block cooperatively
// gathers 8 rows (4 g1 + 4 g2) into SoA LDS via dwordx3 point loads. Masked
// cells are skipped (uniform branch). Plain stores, no atomics, no fences.
__global__ __launch_bounds__(256) void fused_cell_kernel(
    const float* __restrict__ v1s, const float* __restrict__ v2s,
    const int* __restrict__ rid_to_vid, const unsigned char* __restrict__ cm,
    float* __restrict__ minbuf, int N) {
  const int bid = blockIdx.x;              // b*144 + rq*12 + sq
  const int b = bid / 144;
  const int rem = bid % 144;
  const int rq = rem / 12;
  const int sq = rem % 12;
  const int t = threadIdx.x;
  const int w = t >> 6, lane = t & 63;

  __shared__ int stride4_s;
  if (t < 64) {
    const int s4 = detect_stride4(cm, t);
    if (t == 0) stride4_s = s4;
  }

  // cooperative gather: 8 rows x 96 points, 3 points/thread, dwordx3 each
  __shared__ float s1[4][3 * VR_];
  __shared__ float s2[4][3 * VR_];
#pragma unroll
  for (int i = 0; i < 3; ++i) {
    const int p = t + 256 * i;             // 0..767
    const int row8 = p / VR_, v = p % VR_;
    const int g2row = row8 >= 4;
    const int rrow = g2row ? (sq * 4 + row8 - 4) : (rq * 4 + row8);
    const int idx = rid_to_vid[rrow * VR_ + v];
    const F3 pt = *(const F3*)((g2row ? v2s : v1s) + ((size_t)b * N + idx) * 3);
    float* dst = g2row ? s2[row8 - 4] : s1[row8];
    dst[v] = pt.x; dst[VR_ + v] = pt.y; dst[2 * VR_ + v] = pt.z;
  }
  __syncthreads();
  const int stride4 = stride4_s;
  const unsigned int* cm32 = (const unsigned int*)cm;

  // per-wave active mask over its 4 cells (wave-uniform: same addr all lanes)
  const int r = rq * 4 + w;
  const int cellBase = (b * R_ + r) * R_ + sq * 4;
  int actmask = 0;
#pragma unroll
  for (int k = 0; k < 4; ++k) {
    const bool a = stride4 ? (cm32[cellBase + k] != 0u) : (cm[cellBase + k] != 0);
    actmask |= a ? (1 << k) : 0;
  }
  if (!actmask) return;                    // wave-uniform; barriers all done

  const int hi = lane >> 3, lo = lane & 7; // 8x8 lane grid, 12x12 pair tile
  const float* r1 = s1[w];

  float Ax[12], Ay[12], Az[12];
#pragma unroll
  for (int k = 0; k < 3; ++k) {
    *(float4*)&Ax[4 * k] = *(const float4*)(r1           + hi * 12 + 4 * k);
    *(float4*)&Ay[4 * k] = *(const float4*)(r1 +     VR_ + hi * 12 + 4 * k);
    *(float4*)&Az[4 * k] = *(const float4*)(r1 + 2 * VR_ + hi * 12 + 4 * k);
  }

#pragma unroll
  for (int c = 0; c < 4; ++c) {
    if (!(actmask & (1 << c))) continue;   // wave-uniform
    const float* r2 = s2[c];
    v2f Bx[6], By[6], Bz[6];
#pragma unroll
    for (int k = 0; k < 3; ++k) {
      *(float4*)&Bx[2 * k] = *(const float4*)(r2           + lo * 12 + 4 * k);
      *(float4*)&By[2 * k] = *(const float4*)(r2 +     VR_ + lo * 12 + 4 * k);
      *(float4*)&Bz[2 * k] = *(const float4*)(r2 + 2 * VR_ + lo * 12 + 4 * k);
    }
    float acc[4] = {3.4e38f, 3.4e38f, 3.4e38f, 3.4e38f};
#pragma unroll
    for (int i = 0; i < 12; ++i) {
      const v2f axx = {Ax[i], Ax[i]};
      const v2f ayy = {Ay[i], Ay[i]};
      const v2f azz = {Az[i], Az[i]};
#pragma unroll
      for (int j = 0; j < 6; ++j) {
        const v2f dx = axx - Bx[j];
        const v2f dy = ayy - By[j];
        const v2f dz = azz - Bz[j];
        const v2f d2 = dx * dx + dy * dy + dz * dz;
        acc[j & 3] = fminf(acc[j & 3], fminf(d2.x, d2.y));   // v_min3
      }
    }
    float mind2 = fminf(fminf(acc[0], acc[1]), fminf(acc[2], acc[3]));
#pragma unroll
    for (int off = 32; off > 0; off >>= 1)
      mind2 = fminf(mind2, __shfl_down(mind2, off, 64));
    if (lane == 0) minbuf[cellBase + c] = sqrtf(fmaxf(mind2, 0.0f));
  }
}

// ---------------------------------------------------------------------------
// Kernel 2: masked mean per batch (4 blocks). Self-detects cmaps layout.
// Reads only mask-true cells, so poisoned minbuf entries are never touched.
__global__ __launch_bounds__(256) void finalize_kernel(
    const float* __restrict__ min_d, const unsigned char* __restrict__ cm,
    float* __restrict__ out) {
  const int b = blockIdx.x;
  const int t = threadIdx.x;

  __shared__ int stride4_s;
  if (t < 64) {
    const int s4 = detect_stride4(cm, t);
    if (t == 0) stride4_s = s4;
  }
  __syncthreads();
  const int stride4 = stride4_s;
  const unsigned int* cm32 = (const unsigned int*)cm;

  float sum = 0.0f, cnt = 0.0f;
  for (int i = t; i < R_ * R_; i += 256) {
    const int gi = b * R_ * R_ + i;
    const bool m = stride4 ? (cm32[gi] != 0u) : (cm[gi] != 0);
    if (m) { sum += min_d[gi]; cnt += 1.0f; }
  }
#pragma unroll
  for (int off = 32; off > 0; off >>= 1) {
    sum += __shfl_down(sum, off, 64);
    cnt += __shfl_down(cnt, off, 64);
  }
  __shared__ float ws_[4], wc_[4];
  if ((t & 63) == 0) { ws_[t >> 6] = sum; wc_[t >> 6] = cnt; }
  __syncthreads();
  if (t == 0) {
    out[b] = (ws_[0] + ws_[1] + ws_[2] + ws_[3]) /
             (wc_[0] + wc_[1] + wc_[2] + wc_[3]);
  }
}

// ---------------------------------------------------------------------------
extern "C" void kernel_launch(void* const* d_in, const int* in_sizes, int n_in,
                              void* d_out, int out_size, void* d_ws, size_t ws_size,
                              hipStream_t stream) {
  const float* v1s = (const float*)d_in[0];
  const float* v2s = (const float*)d_in[1];
  const unsigned char* cmaps = (const unsigned char*)d_in[2];
  const int* rid_to_vid = (const int*)d_in[3];
  float* out = (float*)d_out;
  float* minbuf = (float*)d_ws;            // 9216 floats = 36 KB

  const int N = in_sizes[0] / (B_ * 3);

  fused_cell_kernel<<<NBLK, 256, 0, stream>>>(
      v1s, v2s, rid_to_vid, cmaps, minbuf, N);
  finalize_kernel<<<B_, 256, 0, stream>>>(minbuf, cmaps, out);
}

// Round 8
// 23.392 us; speedup vs baseline: 1.9565x; 1.1346x over previous
//
#include <hip/hip_runtime.h>

#define B_ 4
#define R_ 48
#define VR_ 96
#define NBLK (B_ * R_ * 12)     // 2304 blocks: (b, r, quad); 4 waves = 4 s-cells

typedef float v2f __attribute__((ext_vector_type(2)));
struct F3 { float x, y, z; };   // 12B, 4B-aligned -> dwordx3 load

// ---------------------------------------------------------------------------
// Detect cmaps element width from its first 256 bytes. Wave-local: each wave
// ballots its own 64 dwords (L1-hit after first wave) -> no shared var, no
// barrier. int32 layout: bytes at i%4!=0 all zero; f32 layout: contains
// 0x80/0x3F exponent bytes; bool layout: random 0/1 bytes, some nonzero,
// none > 1. Deterministic for fixed inputs.
__device__ __forceinline__ int detect_stride4(const unsigned char* cm, int lane) {
  const unsigned int d = ((const unsigned int*)cm)[lane];
  const unsigned int b1 = (d >> 8) & 0xff, b2 = (d >> 16) & 0xff, b3 = d >> 24;
  const unsigned long long nzm = __ballot((b1 | b2 | b3) != 0);
  const unsigned long long bigm = __ballot((b1 > 1) || (b2 > 1) || (b3 > 1));
  return (bigm != 0ull || nzm == 0ull) ? 1 : 0;
}

// ---------------------------------------------------------------------------
// Kernel 1: fused gather + min-distance. One wave per (b,r,s) cell, 4 cells
// per block sharing the g1 row. Gather loads are issued FIRST (into regs,
// independent of cmaps) so their latency overlaps the mask/detect loads;
// single barrier; per-wave masked exit after it. Plain stores only.
__global__ __launch_bounds__(256) void fused_cell_kernel(
    const float* __restrict__ v1s, const float* __restrict__ v2s,
    const int* __restrict__ rid_to_vid, const unsigned char* __restrict__ cm,
    float* __restrict__ minbuf, int N) {
  const int bid = blockIdx.x;              // b*(48*12) + r*12 + quad
  const int b = bid / (R_ * 12);
  const int rem = bid % (R_ * 12);
  const int r = rem / 12;
  const int quad = rem % 12;
  const int t = threadIdx.x;
  const int w = t >> 6, lane = t & 63;
  const int s = quad * 4 + w;
  const int cellIdx = (b * R_ + r) * R_ + s;
  const size_t bN3 = (size_t)b * N * 3;

  // ---- issue all gather loads first (no cmaps dependency) ----
  // g1 row r: threads 0..95, one point each.
  F3 pt1;
  const bool have1 = (t < VR_);
  if (have1) {
    const int idx = rid_to_vid[r * VR_ + t];
    pt1 = *(const F3*)(v1s + bN3 + (size_t)idx * 3);
  }
  // g2 rows quad*4..quad*4+3 (384 points): p = t and t+256.
  const int row0 = t / VR_, v0 = t % VR_;
  const int idx0 = rid_to_vid[(quad * 4 + row0) * VR_ + v0];
  const F3 pt2a = *(const F3*)(v2s + bN3 + (size_t)idx0 * 3);
  const int p1 = t + 256;
  const bool have2b = (p1 < 4 * VR_);
  int row1 = 3, v1 = 0;
  F3 pt2b;
  if (have2b) {
    row1 = p1 / VR_; v1 = p1 % VR_;
    const int idx1 = rid_to_vid[(quad * 4 + row1) * VR_ + v1];
    pt2b = *(const F3*)(v2s + bN3 + (size_t)idx1 * 3);
  }

  // ---- overlap: mask layout detect + this wave's cell mask ----
  const int stride4 = detect_stride4(cm, lane);
  const bool active = stride4 ? (((const unsigned int*)cm)[cellIdx] != 0u)
                              : (cm[cellIdx] != 0);

  // ---- LDS SoA stores + single barrier ----
  __shared__ float s1[3 * VR_];
  __shared__ float s2[4][3 * VR_];
  if (have1) { s1[t] = pt1.x; s1[VR_ + t] = pt1.y; s1[2 * VR_ + t] = pt1.z; }
  s2[row0][v0] = pt2a.x; s2[row0][VR_ + v0] = pt2a.y; s2[row0][2 * VR_ + v0] = pt2a.z;
  if (have2b) { s2[row1][v1] = pt2b.x; s2[row1][VR_ + v1] = pt2b.y; s2[row1][2 * VR_ + v1] = pt2b.z; }
  __syncthreads();

  if (!active) return;                      // wave-uniform, after the barrier

  const float* r2 = s2[w];
  const int hi = lane >> 3, lo = lane & 7;  // 8x8 lane grid, 12x12 pair tile

  float Ax[12], Ay[12], Az[12];
  v2f Bx[6], By[6], Bz[6];
#pragma unroll
  for (int k = 0; k < 3; ++k) {
    *(float4*)&Ax[4 * k] = *(const float4*)(s1           + hi * 12 + 4 * k);
    *(float4*)&Ay[4 * k] = *(const float4*)(s1 +     VR_ + hi * 12 + 4 * k);
    *(float4*)&Az[4 * k] = *(const float4*)(s1 + 2 * VR_ + hi * 12 + 4 * k);
    *(float4*)&Bx[2 * k] = *(const float4*)(r2           + lo * 12 + 4 * k);
    *(float4*)&By[2 * k] = *(const float4*)(r2 +     VR_ + lo * 12 + 4 * k);
    *(float4*)&Bz[2 * k] = *(const float4*)(r2 + 2 * VR_ + lo * 12 + 4 * k);
  }

  float acc[4] = {3.4e38f, 3.4e38f, 3.4e38f, 3.4e38f};
#pragma unroll
  for (int i = 0; i < 12; ++i) {
    const v2f axx = {Ax[i], Ax[i]};
    const v2f ayy = {Ay[i], Ay[i]};
    const v2f azz = {Az[i], Az[i]};
#pragma unroll
    for (int j = 0; j < 6; ++j) {
      const v2f dx = axx - Bx[j];
      const v2f dy = ayy - By[j];
      const v2f dz = azz - Bz[j];
      const v2f d2 = dx * dx + dy * dy + dz * dz;
      acc[j & 3] = fminf(acc[j & 3], fminf(d2.x, d2.y));   // v_min3
    }
  }
  float mind2 = fminf(fminf(acc[0], acc[1]), fminf(acc[2], acc[3]));
#pragma unroll
  for (int off = 32; off > 0; off >>= 1)
    mind2 = fminf(mind2, __shfl_down(mind2, off, 64));
  if (lane == 0) minbuf[cellIdx] = sqrtf(fmaxf(mind2, 0.0f));
}

// ---------------------------------------------------------------------------
// Kernel 2: masked mean per batch (4 blocks). Per-wave layout detect (no
// extra barrier). Reads only mask-true cells, so poisoned minbuf entries for
// masked cells are never touched.
__global__ __launch_bounds__(256) void finalize_kernel(
    const float* __restrict__ min_d, const unsigned char* __restrict__ cm,
    float* __restrict__ out) {
  const int b = blockIdx.x;
  const int t = threadIdx.x;
  const int lane = t & 63;

  const int stride4 = detect_stride4(cm, lane);
  const unsigned int* cm32 = (const unsigned int*)cm;

  float sum = 0.0f, cnt = 0.0f;
  for (int i = t; i < R_ * R_; i += 256) {
    const int gi = b * R_ * R_ + i;
    const bool m = stride4 ? (cm32[gi] != 0u) : (cm[gi] != 0);
    if (m) { sum += min_d[gi]; cnt += 1.0f; }
  }
#pragma unroll
  for (int off = 32; off > 0; off >>= 1) {
    sum += __shfl_down(sum, off, 64);
    cnt += __shfl_down(cnt, off, 64);
  }
  __shared__ float ws_[4], wc_[4];
  if ((t & 63) == 0) { ws_[t >> 6] = sum; wc_[t >> 6] = cnt; }
  __syncthreads();
  if (t == 0) {
    out[b] = (ws_[0] + ws_[1] + ws_[2] + ws_[3]) /
             (wc_[0] + wc_[1] + wc_[2] + wc_[3]);
  }
}

// ---------------------------------------------------------------------------
extern "C" void kernel_launch(void* const* d_in, const int* in_sizes, int n_in,
                              void* d_out, int out_size, void* d_ws, size_t ws_size,
                              hipStream_t stream) {
  const float* v1s = (const float*)d_in[0];
  const float* v2s = (const float*)d_in[1];
  const unsigned char* cmaps = (const unsigned char*)d_in[2];
  const int* rid_to_vid = (const int*)d_in[3];
  float* out = (float*)d_out;
  float* minbuf = (float*)d_ws;            // 9216 floats = 36 KB

  const int N = in_sizes[0] / (B_ * 3);

  fused_cell_kernel<<<NBLK, 256, 0, stream>>>(
      v1s, v2s, rid_to_vid, cmaps, minbuf, N);
  finalize_kernel<<<B_, 256, 0, stream>>>(minbuf, cmaps, out);
}